// Round 2
// baseline (237.794 us; speedup 1.0000x reference)
//
#include <hip/hip_runtime.h>
#include <hip/hip_bf16.h>

typedef unsigned short u16;
typedef __attribute__((ext_vector_type(8))) short bf16x8;
typedef __attribute__((ext_vector_type(4))) float f32x4;

#define BDIM 4096
#define DDIM 1024
#define UDIM 1024
#define NE 8
#define NDIM 8192  // U*E
#define RL_CAP 4224  // per-expert rowlist capacity (4096 rounded up + pad slack)
#define MAX_JOBS 71  // max sum of ceil(cnt_e/128): floor(8192/128)+7

__device__ __forceinline__ u16 f2bf(float f) {
    unsigned int u = __float_as_uint(f);
    u += 0x7fffu + ((u >> 16) & 1u);   // round-to-nearest-even
    return (u16)(u >> 16);
}

__device__ __forceinline__ void gload_lds16(const u16* g, u16* lds) {
    __builtin_amdgcn_global_load_lds(
        (const __attribute__((address_space(1))) void*)g,
        (__attribute__((address_space(3))) void*)lds, 16, 0, 0);
}

// ---------------- zero counters ----------------
__global__ __launch_bounds__(64) void zero_cnt_kernel(int* __restrict__ cnt) {
    if (threadIdx.x < 8) cnt[threadIdx.x] = 0;
}

// ---------------- pre-pass: x f32 -> bf16 ----------------
__global__ __launch_bounds__(256) void convert_x_kernel(
    const float* __restrict__ in, u16* __restrict__ out, int n4)
{
    int i = blockIdx.x * 256 + threadIdx.x;
    if (i < n4) {
        float4 v = ((const float4*)in)[i];
        ushort4 o;
        o.x = f2bf(v.x); o.y = f2bf(v.y); o.z = f2bf(v.z); o.w = f2bf(v.w);
        ((ushort4*)out)[i] = o;
    }
}

// ---------------- pre-pass: mu [D][N] f32 -> mu_t [N][D] bf16 (tiled transpose) ----------------
__global__ __launch_bounds__(256) void convert_mu_t_kernel(
    const float* __restrict__ mu, u16* __restrict__ mut)
{
    __shared__ u16 tile[64 * 66];
    const int n0 = blockIdx.x * 64;
    const int d0 = blockIdx.y * 64;
    const int tid = threadIdx.x;
    const int nl = tid & 63;
#pragma unroll
    for (int i = 0; i < 16; ++i) {
        int dl = i * 4 + (tid >> 6);
        tile[dl * 66 + nl] = f2bf(mu[(size_t)(d0 + dl) * NDIM + n0 + nl]);
    }
    __syncthreads();
#pragma unroll
    for (int issue = 0; issue < 2; ++issue) {
        int nloc = issue * 32 + (tid >> 3);
        int d8 = (tid & 7) * 8;
        uint4 o;
        u16* tp = (u16*)&o;
#pragma unroll
        for (int i = 0; i < 8; ++i) tp[i] = tile[(d8 + i) * 66 + nloc];
        *(uint4*)&mut[(size_t)(n0 + nloc) * DDIM + d0 + d8] = o;
    }
}

// ---------------- pre-pass: se[n] = softplus(rho)*eps ----------------
__global__ __launch_bounds__(256) void prep_se_kernel(
    const float* __restrict__ rho, const float* __restrict__ eps,
    float* __restrict__ se, int n)
{
    int i = blockIdx.x * 256 + threadIdx.x;
    if (i < n) {
        float r = rho[i];
        se[i] = log1pf(expf(r)) * eps[i];
    }
}

// ---------------- gating: top2 softmax renorm, xsum, expert row lists ----------------
__global__ __launch_bounds__(256) void gating_kernel(
    const float* __restrict__ x, const float* __restrict__ gk,
    const float* __restrict__ gb, float* __restrict__ gw,
    float* __restrict__ xsum, int4* __restrict__ pkb,
    int* __restrict__ cnt, u16* __restrict__ rowlist)
{
    const int b = blockIdx.x * 4 + (threadIdx.x >> 6);
    const int lane = threadIdx.x & 63;
    float acc[8] = {0.f,0.f,0.f,0.f,0.f,0.f,0.f,0.f};
    float xs = 0.f;
    for (int d = lane; d < DDIM; d += 64) {
        float xv = x[(size_t)b * DDIM + d];
        xs += xv;
        const float4* g4 = (const float4*)&gk[d * NE];
        float4 g0 = g4[0], g1 = g4[1];
        acc[0] += xv * g0.x; acc[1] += xv * g0.y; acc[2] += xv * g0.z; acc[3] += xv * g0.w;
        acc[4] += xv * g1.x; acc[5] += xv * g1.y; acc[6] += xv * g1.z; acc[7] += xv * g1.w;
    }
#pragma unroll
    for (int off = 32; off >= 1; off >>= 1) {
        xs += __shfl_xor(xs, off);
#pragma unroll
        for (int e = 0; e < 8; ++e) acc[e] += __shfl_xor(acc[e], off);
    }
    if (lane == 0) {
        float lg[8];
#pragma unroll
        for (int e = 0; e < 8; ++e) lg[e] = acc[e] + gb[e];
        int i1 = 0;
#pragma unroll
        for (int e = 1; e < 8; ++e) if (lg[e] > lg[i1]) i1 = e;   // first-occurrence argmax
        int i2 = (i1 == 0) ? 1 : 0;
#pragma unroll
        for (int e = 0; e < 8; ++e) {
            if (e == i1 || e == i2) continue;
            if (lg[e] > lg[i2]) i2 = e;
        }
        float p1 = 1.f / (1.f + expf(lg[i2] - lg[i1]));  // renorm top-2 == softmax over {l1,l2}
        float p2 = 1.f - p1;
        float out[8] = {0.f,0.f,0.f,0.f,0.f,0.f,0.f,0.f};
        out[i1] = p1; out[i2] = p2;
#pragma unroll
        for (int e = 0; e < 8; ++e) gw[b * NE + e] = out[e];
        xsum[b] = xs;
        pkb[b] = make_int4(i1, i2, __float_as_int(p1), __float_as_int(p2));
        int pos1 = atomicAdd(&cnt[i1], 1);
        rowlist[i1 * RL_CAP + pos1] = (u16)b;
        int pos2 = atomicAdd(&cnt[i2], 1);
        rowlist[i2 * RL_CAP + pos2] = (u16)b;
    }
}

// ---------------- builder: pad rowlists to x128, emit job list ----------------
__global__ __launch_bounds__(256) void build_jobs_kernel(
    const int* __restrict__ cnt, int* __restrict__ njobs,
    int* __restrict__ jobs, u16* __restrict__ rowlist)
{
    __shared__ int sc[8], spc[8], sbase[9];
    const int tid = threadIdx.x;
    if (tid < 8) {
        int c = cnt[tid];
        sc[tid] = c;
        spc[tid] = (c + 127) >> 7;   // m-tiles for this expert
    }
    __syncthreads();
    if (tid == 0) {
        sbase[0] = 0;
        for (int e = 0; e < 8; ++e) sbase[e + 1] = sbase[e] + spc[e];
        *njobs = sbase[8];
    }
    __syncthreads();
    // emit jobs
    if (tid < 8) {
        int e = tid;
        for (int t = 0; t < spc[e]; ++t)
            jobs[sbase[e] + t] = (e << 16) | (t << 7);   // (expert, slot base)
    }
    // pad rowlists with sentinel
    for (int e = 0; e < 8; ++e) {
        int c = sc[e], pc = spc[e] << 7;
        for (int i = c + tid; i < pc; i += 256)
            rowlist[e * RL_CAP + i] = (u16)0xFFFF;
    }
}

// ---------------- y init: noise + bias term  y[b,u] = sum_top2 w*(xsum*se + bias) ----------------
__global__ __launch_bounds__(256) void y_init_kernel(
    const int4* __restrict__ pkb, const float* __restrict__ xsum,
    const float* __restrict__ se, const float* __restrict__ biasv,
    float* __restrict__ y)
{
    int idx = blockIdx.x * 256 + threadIdx.x;   // over B * U/4
    int b = idx >> 8;
    int u4 = (idx & 255) * 4;
    int4 pk = pkb[b];
    float w1 = __int_as_float(pk.z), w2 = __int_as_float(pk.w);
    float xs = xsum[b];
    float4 o;
#pragma unroll
    for (int t = 0; t < 4; ++t) {
        int u = u4 + t;
        int n1 = u * NE + pk.x, n2 = u * NE + pk.y;
        ((float*)&o)[t] = w1 * (xs * se[n1] + biasv[n1]) + w2 * (xs * se[n2] + biasv[n2]);
    }
    *(float4*)&y[(size_t)b * UDIM + u4] = o;
}

// ---------------- grouped GEMM: per expert, gathered rows, scatter atomicAdd ----------------
// m97 structure: 128x128 tile, BK=64, 4 waves (2x2), global_load_lds w16.
__global__ __launch_bounds__(256) void gemm_grouped_kernel(
    const u16* __restrict__ Xb,      // [4096][1024] bf16
    const u16* __restrict__ Wt,      // [8192][1024] bf16, row n = u*8+e
    const float* __restrict__ gw,    // [4096][8]
    const int* __restrict__ jobs,
    const int* __restrict__ njobs,
    const u16* __restrict__ rowlist, // [8][RL_CAP]
    float* __restrict__ y)           // [4096][1024]
{
    const int j = blockIdx.y;
    if (j >= *njobs) return;
    const int job = jobs[j];
    const int e  = job >> 16;
    const int m0 = job & 0xFFFF;
    const int u0 = blockIdx.x * 128;

    __shared__ u16 As[128 * 64];
    __shared__ u16 Bs[128 * 64];

    const int tid  = threadIdx.x;
    const int lane = tid & 63;
    const int wid  = tid >> 6;
    const int wm = wid >> 1, wn = wid & 1;
    const int l15 = lane & 15;
    const int l4  = lane >> 4;

    const u16* __restrict__ rowl = rowlist + e * RL_CAP + m0;

    const int stg_r  = tid >> 3;        // 0..31
    const int stg_c8 = (tid & 7) * 8;   // 0..56

    // precompute per-thread staging sources (gathered A rows; strided B rows)
    const u16* aP[4];
    const u16* bP[4];
#pragma unroll
    for (int it = 0; it < 4; ++it) {
        int r = it * 32 + stg_r;
        int rid = rowl[r];
        if (rid == 0xFFFF) rid = 0;     // padded slot: load something valid
        aP[it] = Xb + (size_t)rid * DDIM + stg_c8;
        bP[it] = Wt + ((size_t)(u0 + r) * NE + e) * DDIM + stg_c8;
    }

    f32x4 acc[4][4] = {};

    for (int kk = 0; kk < DDIM; kk += 64) {
#pragma unroll
        for (int it = 0; it < 4; ++it) {
            int r = it * 32 + stg_r;
            gload_lds16(aP[it] + kk, &As[r * 64 + stg_c8]);
            gload_lds16(bP[it] + kk, &Bs[r * 64 + stg_c8]);
        }
        __syncthreads();
#pragma unroll
        for (int k2 = 0; k2 < 2; ++k2) {
            bf16x8 av[4], bv[4];
#pragma unroll
            for (int m = 0; m < 4; ++m)
                av[m] = *(const bf16x8*)&As[(wm * 64 + m * 16 + l15) * 64 + k2 * 32 + l4 * 8];
#pragma unroll
            for (int n = 0; n < 4; ++n)
                bv[n] = *(const bf16x8*)&Bs[(wn * 64 + n * 16 + l15) * 64 + k2 * 32 + l4 * 8];
#pragma unroll
            for (int m = 0; m < 4; ++m)
#pragma unroll
                for (int n = 0; n < 4; ++n)
                    acc[m][n] = __builtin_amdgcn_mfma_f32_16x16x32_bf16(av[m], bv[n], acc[m][n], 0, 0, 0);
        }
        __syncthreads();
    }

    // Epilogue: y[b, u] += gw[b,e] * dot   (C/D layout: col=lane&15, row=(lane>>4)*4+j)
#pragma unroll
    for (int m = 0; m < 4; ++m) {
#pragma unroll
        for (int jj = 0; jj < 4; ++jj) {
            int r_loc = wm * 64 + m * 16 + l4 * 4 + jj;
            u16 b16 = rowl[r_loc];
            if (b16 == (u16)0xFFFF) continue;
            float w = gw[(int)b16 * NE + e];
            float* yrow = &y[(size_t)b16 * UDIM];
#pragma unroll
            for (int n = 0; n < 4; ++n) {
                int u = u0 + wn * 64 + n * 16 + l15;
                atomicAdd(&yrow[u], w * acc[m][n][jj]);
            }
        }
    }
}

extern "C" void kernel_launch(void* const* d_in, const int* in_sizes, int n_in,
                              void* d_out, int out_size, void* d_ws, size_t ws_size,
                              hipStream_t stream) {
    const float* x    = (const float*)d_in[0];
    const float* mu   = (const float*)d_in[1];
    const float* rho  = (const float*)d_in[2];
    const float* bias = (const float*)d_in[3];
    const float* gk   = (const float*)d_in[4];
    const float* gb   = (const float*)d_in[5];
    const float* eps  = (const float*)d_in[6];
    float* y = (float*)d_out;

    char* ws = (char*)d_ws;
    u16*   mu_t = (u16*)ws;                       // 16,777,216
    u16*   xb   = (u16*)(ws + 16777216);          //  8,388,608 -> 25165824
    float* gwp  = (float*)(ws + 25165824);        //    131,072 -> 25296896
    float* xsp  = (float*)(ws + 25296896);        //     16,384 -> 25313280
    float* sep  = (float*)(ws + 25313280);        //     32,768 -> 25346048
    int*   cnt  = (int*)(ws + 25346048);          //         32 -> 25346080
    int*   njb  = (int*)(ws + 25346080);          //          4 -> 25346084
    int*   jobs = (int*)(ws + 25346176);          //        288 -> 25346464
    int4*  pkb  = (int4*)(ws + 25346560);         //     65,536 -> 25412096
    u16*   rowl = (u16*)(ws + 25412096);          //     67,584 -> 25479680
    if (ws_size < 25479680) return;

    zero_cnt_kernel<<<dim3(1), dim3(64), 0, stream>>>(cnt);
    convert_x_kernel<<<dim3(4096), dim3(256), 0, stream>>>(x, xb, (BDIM * DDIM) / 4);
    convert_mu_t_kernel<<<dim3(NDIM / 64, DDIM / 64), dim3(256), 0, stream>>>(mu, mu_t);
    prep_se_kernel<<<dim3(32), dim3(256), 0, stream>>>(rho, eps, sep, NDIM);
    gating_kernel<<<dim3(BDIM / 4), dim3(256), 0, stream>>>(x, gk, gb, gwp, xsp, pkb, cnt, rowl);
    build_jobs_kernel<<<dim3(1), dim3(256), 0, stream>>>(cnt, njb, jobs, rowl);
    y_init_kernel<<<dim3(BDIM * (UDIM / 4) / 256), dim3(256), 0, stream>>>(pkb, xsp, sep, bias, y);
    gemm_grouped_kernel<<<dim3(UDIM / 128, MAX_JOBS), dim3(256), 0, stream>>>(
        xb, mu_t, gwp, jobs, njb, rowl, y);
}

// Round 3
// 150.795 us; speedup vs baseline: 1.5769x; 1.5769x over previous
//
#include <hip/hip_runtime.h>
#include <hip/hip_bf16.h>

typedef unsigned short u16;
typedef __attribute__((ext_vector_type(8))) short bf16x8;
typedef __attribute__((ext_vector_type(4))) float f32x4;

#define BDIM 4096
#define DDIM 1024
#define UDIM 1024
#define NE 8
#define NDIM 8192    // U*E
#define RL_CAP 4224  // per-expert rowlist capacity (4096 rounded to 128 + slack)

__device__ __forceinline__ u16 f2bf(float f) {
    unsigned int u = __float_as_uint(f);
    u += 0x7fffu + ((u >> 16) & 1u);   // round-to-nearest-even
    return (u16)(u >> 16);
}

__device__ __forceinline__ void gload_lds16(const u16* g, u16* lds) {
    __builtin_amdgcn_global_load_lds(
        (const __attribute__((address_space(1))) void*)g,
        (__attribute__((address_space(3))) void*)lds, 16, 0, 0);
}

// ---------------- pre-pass: x f32 -> bf16 ----------------
__global__ __launch_bounds__(256) void convert_x_kernel(
    const float* __restrict__ in, u16* __restrict__ out, int n4)
{
    int i = blockIdx.x * 256 + threadIdx.x;
    if (i < n4) {
        float4 v = ((const float4*)in)[i];
        ushort4 o;
        o.x = f2bf(v.x); o.y = f2bf(v.y); o.z = f2bf(v.z); o.w = f2bf(v.w);
        ((ushort4*)out)[i] = o;
    }
}

// ---------------- pre-pass: mu [D][N] f32 -> mu_t [N][D] bf16 (tiled transpose) ----------------
__global__ __launch_bounds__(256) void convert_mu_t_kernel(
    const float* __restrict__ mu, u16* __restrict__ mut)
{
    __shared__ u16 tile[64 * 66];
    const int n0 = blockIdx.x * 64;
    const int d0 = blockIdx.y * 64;
    const int tid = threadIdx.x;
    const int nl = tid & 63;
#pragma unroll
    for (int i = 0; i < 16; ++i) {
        int dl = i * 4 + (tid >> 6);
        tile[dl * 66 + nl] = f2bf(mu[(size_t)(d0 + dl) * NDIM + n0 + nl]);
    }
    __syncthreads();
#pragma unroll
    for (int issue = 0; issue < 2; ++issue) {
        int nloc = issue * 32 + (tid >> 3);
        int d8 = (tid & 7) * 8;
        uint4 o;
        u16* tp = (u16*)&o;
#pragma unroll
        for (int i = 0; i < 8; ++i) tp[i] = tile[(d8 + i) * 66 + nloc];
        *(uint4*)&mut[(size_t)(n0 + nloc) * DDIM + d0 + d8] = o;
    }
}

// ---------------- pre-pass: se[n] = softplus(rho)*eps ----------------
__global__ __launch_bounds__(256) void prep_se_kernel(
    const float* __restrict__ rho, const float* __restrict__ eps,
    float* __restrict__ se, int n)
{
    int i = blockIdx.x * 256 + threadIdx.x;
    if (i < n) {
        float r = rho[i];
        se[i] = log1pf(expf(r)) * eps[i];
    }
}

// ---------------- gating: top2 softmax renorm, xsum, pkb (NO atomics) ----------------
__global__ __launch_bounds__(256) void gating_kernel(
    const float* __restrict__ x, const float* __restrict__ gk,
    const float* __restrict__ gb, float* __restrict__ gw,
    float* __restrict__ xsum, int4* __restrict__ pkb)
{
    const int b = blockIdx.x * 4 + (threadIdx.x >> 6);
    const int lane = threadIdx.x & 63;
    float acc[8] = {0.f,0.f,0.f,0.f,0.f,0.f,0.f,0.f};
    float xs = 0.f;
    for (int d = lane; d < DDIM; d += 64) {
        float xv = x[(size_t)b * DDIM + d];
        xs += xv;
        const float4* g4 = (const float4*)&gk[d * NE];
        float4 g0 = g4[0], g1 = g4[1];
        acc[0] += xv * g0.x; acc[1] += xv * g0.y; acc[2] += xv * g0.z; acc[3] += xv * g0.w;
        acc[4] += xv * g1.x; acc[5] += xv * g1.y; acc[6] += xv * g1.z; acc[7] += xv * g1.w;
    }
#pragma unroll
    for (int off = 32; off >= 1; off >>= 1) {
        xs += __shfl_xor(xs, off);
#pragma unroll
        for (int e = 0; e < 8; ++e) acc[e] += __shfl_xor(acc[e], off);
    }
    if (lane == 0) {
        float lg[8];
#pragma unroll
        for (int e = 0; e < 8; ++e) lg[e] = acc[e] + gb[e];
        int i1 = 0;
#pragma unroll
        for (int e = 1; e < 8; ++e) if (lg[e] > lg[i1]) i1 = e;   // first-occurrence argmax
        int i2 = (i1 == 0) ? 1 : 0;
#pragma unroll
        for (int e = 0; e < 8; ++e) {
            if (e == i1 || e == i2) continue;
            if (lg[e] > lg[i2]) i2 = e;
        }
        float p1 = 1.f / (1.f + expf(lg[i2] - lg[i1]));  // renorm top-2 == softmax over {l1,l2}
        float p2 = 1.f - p1;
        float out[8] = {0.f,0.f,0.f,0.f,0.f,0.f,0.f,0.f};
        out[i1] = p1; out[i2] = p2;
#pragma unroll
        for (int e = 0; e < 8; ++e) gw[b * NE + e] = out[e];
        xsum[b] = xs;
        pkb[b] = make_int4(i1, i2, __float_as_int(p1), __float_as_int(p2));
    }
}

// ---------------- rowlist builder: per-expert ordered compaction via wave scan ----------------
__global__ __launch_bounds__(256) void build_rowlist_kernel(
    const int4* __restrict__ pkb, int* __restrict__ cnt,
    u16* __restrict__ rowlist)
{
    const int e = blockIdx.x;          // 0..7
    const int tid = threadIdx.x;
    const int wv = tid >> 6, lane = tid & 63;
    __shared__ int wsum[4];
    __shared__ int sbase;
    if (tid == 0) sbase = 0;
    __syncthreads();
    u16* rl = rowlist + e * RL_CAP;
    for (int chunk = 0; chunk < BDIM; chunk += 256) {
        int b = chunk + tid;
        int4 pk = pkb[b];
        bool f = (pk.x == e) || (pk.y == e);
        unsigned long long m = __ballot(f);
        int prefix = __popcll(m & ((1ULL << lane) - 1ULL));
        if (lane == 0) wsum[wv] = __popcll(m);
        __syncthreads();
        int wbase = sbase;
        for (int w = 0; w < wv; ++w) wbase += wsum[w];
        if (f) rl[wbase + prefix] = (u16)b;
        __syncthreads();
        if (tid == 0) sbase += wsum[0] + wsum[1] + wsum[2] + wsum[3];
        __syncthreads();
    }
    // pad to multiple of 128 with sentinel; publish count
    int c = sbase;
    int pc = (c + 127) & ~127;
    for (int i = c + tid; i < pc; i += 256) rl[i] = (u16)0xFFFF;
    if (tid == 0) cnt[e] = c;
}

// ---------------- y init: noise + bias term  y[b,u] = sum_top2 w*(xsum*se + bias) ----------------
__global__ __launch_bounds__(256) void y_init_kernel(
    const int4* __restrict__ pkb, const float* __restrict__ xsum,
    const float* __restrict__ se, const float* __restrict__ biasv,
    float* __restrict__ y)
{
    int idx = blockIdx.x * 256 + threadIdx.x;   // over B * U/4
    int b = idx >> 8;
    int u4 = (idx & 255) * 4;
    int4 pk = pkb[b];
    float w1 = __int_as_float(pk.z), w2 = __int_as_float(pk.w);
    float xs = xsum[b];
    float4 o;
#pragma unroll
    for (int t = 0; t < 4; ++t) {
        int u = u4 + t;
        int n1 = u * NE + pk.x, n2 = u * NE + pk.y;
        ((float*)&o)[t] = w1 * (xs * se[n1] + biasv[n1]) + w2 * (xs * se[n2] + biasv[n2]);
    }
    *(float4*)&y[(size_t)b * UDIM + u4] = o;
}

// ---------------- grouped GEMM: per expert, gathered rows, scatter atomicAdd ----------------
// m97 structure: 128x128 tile, BK=64, 4 waves (2x2), global_load_lds w16.
// blockIdx.y encodes (expert e = y>>5, m-tile t = y&31); early-exit if t*128 >= cnt[e].
__global__ __launch_bounds__(256) void gemm_grouped_kernel(
    const u16* __restrict__ Xb,      // [4096][1024] bf16
    const u16* __restrict__ Wt,      // [8192][1024] bf16, row n = u*8+e
    const float* __restrict__ gw,    // [4096][8]
    const int* __restrict__ cnt,     // [8]
    const u16* __restrict__ rowlist, // [8][RL_CAP]
    float* __restrict__ y)           // [4096][1024]
{
    const int e  = blockIdx.y >> 5;
    const int m0 = (blockIdx.y & 31) << 7;
    if (m0 >= cnt[e]) return;
    const int u0 = blockIdx.x * 128;

    __shared__ u16 As[128 * 64];
    __shared__ u16 Bs[128 * 64];

    const int tid  = threadIdx.x;
    const int lane = tid & 63;
    const int wid  = tid >> 6;
    const int wm = wid >> 1, wn = wid & 1;
    const int l15 = lane & 15;
    const int l4  = lane >> 4;

    const u16* __restrict__ rowl = rowlist + e * RL_CAP + m0;

    const int stg_r  = tid >> 3;        // 0..31
    const int stg_c8 = (tid & 7) * 8;   // 0..56

    const u16* aP[4];
    const u16* bP[4];
#pragma unroll
    for (int it = 0; it < 4; ++it) {
        int r = it * 32 + stg_r;
        int rid = rowl[r];
        if (rid == 0xFFFF) rid = 0;     // padded slot: load something valid
        aP[it] = Xb + (size_t)rid * DDIM + stg_c8;
        bP[it] = Wt + ((size_t)(u0 + r) * NE + e) * DDIM + stg_c8;
    }

    f32x4 acc[4][4] = {};

    for (int kk = 0; kk < DDIM; kk += 64) {
#pragma unroll
        for (int it = 0; it < 4; ++it) {
            int r = it * 32 + stg_r;
            gload_lds16(aP[it] + kk, &As[r * 64 + stg_c8]);
            gload_lds16(bP[it] + kk, &Bs[r * 64 + stg_c8]);
        }
        __syncthreads();
#pragma unroll
        for (int k2 = 0; k2 < 2; ++k2) {
            bf16x8 av[4], bv[4];
#pragma unroll
            for (int m = 0; m < 4; ++m)
                av[m] = *(const bf16x8*)&As[(wm * 64 + m * 16 + l15) * 64 + k2 * 32 + l4 * 8];
#pragma unroll
            for (int n = 0; n < 4; ++n)
                bv[n] = *(const bf16x8*)&Bs[(wn * 64 + n * 16 + l15) * 64 + k2 * 32 + l4 * 8];
#pragma unroll
            for (int m = 0; m < 4; ++m)
#pragma unroll
                for (int n = 0; n < 4; ++n)
                    acc[m][n] = __builtin_amdgcn_mfma_f32_16x16x32_bf16(av[m], bv[n], acc[m][n], 0, 0, 0);
        }
        __syncthreads();
    }

    // Epilogue: y[b, u] += gw[b,e] * dot   (C/D layout: col=lane&15, row=(lane>>4)*4+j)
#pragma unroll
    for (int m = 0; m < 4; ++m) {
#pragma unroll
        for (int jj = 0; jj < 4; ++jj) {
            int r_loc = wm * 64 + m * 16 + l4 * 4 + jj;
            u16 b16 = rowl[r_loc];
            if (b16 == (u16)0xFFFF) continue;
            float w = gw[(int)b16 * NE + e];
            float* yrow = &y[(size_t)b16 * UDIM];
#pragma unroll
            for (int n = 0; n < 4; ++n) {
                int u = u0 + wn * 64 + n * 16 + l15;
                atomicAdd(&yrow[u], w * acc[m][n][jj]);
            }
        }
    }
}

extern "C" void kernel_launch(void* const* d_in, const int* in_sizes, int n_in,
                              void* d_out, int out_size, void* d_ws, size_t ws_size,
                              hipStream_t stream) {
    const float* x    = (const float*)d_in[0];
    const float* mu   = (const float*)d_in[1];
    const float* rho  = (const float*)d_in[2];
    const float* bias = (const float*)d_in[3];
    const float* gk   = (const float*)d_in[4];
    const float* gb   = (const float*)d_in[5];
    const float* eps  = (const float*)d_in[6];
    float* y = (float*)d_out;

    char* ws = (char*)d_ws;
    u16*   mu_t = (u16*)ws;                       // 16,777,216
    u16*   xb   = (u16*)(ws + 16777216);          //  8,388,608 -> 25165824
    float* gwp  = (float*)(ws + 25165824);        //    131,072 -> 25296896
    float* xsp  = (float*)(ws + 25296896);        //     16,384 -> 25313280
    float* sep  = (float*)(ws + 25313280);        //     32,768 -> 25346048
    int*   cnt  = (int*)(ws + 25346048);          //         32 -> 25346080
    int4*  pkb  = (int4*)(ws + 25346560);         //     65,536 -> 25412096
    u16*   rowl = (u16*)(ws + 25412096);          //     67,584 -> 25479680
    if (ws_size < 25479680) return;

    convert_x_kernel<<<dim3(4096), dim3(256), 0, stream>>>(x, xb, (BDIM * DDIM) / 4);
    convert_mu_t_kernel<<<dim3(NDIM / 64, DDIM / 64), dim3(256), 0, stream>>>(mu, mu_t);
    prep_se_kernel<<<dim3(32), dim3(256), 0, stream>>>(rho, eps, sep, NDIM);
    gating_kernel<<<dim3(BDIM / 4), dim3(256), 0, stream>>>(x, gk, gb, gwp, xsp, pkb);
    build_rowlist_kernel<<<dim3(8), dim3(256), 0, stream>>>(pkb, cnt, rowl);
    y_init_kernel<<<dim3(BDIM * (UDIM / 4) / 256), dim3(256), 0, stream>>>(pkb, xsp, sep, bias, y);
    gemm_grouped_kernel<<<dim3(UDIM / 128, 256), dim3(256), 0, stream>>>(
        xb, mu_t, gwp, cnt, rowl, y);
}

// Round 4
// 121.231 us; speedup vs baseline: 1.9615x; 1.2439x over previous
//
#include <hip/hip_runtime.h>
#include <hip/hip_bf16.h>

typedef unsigned short u16;
typedef __attribute__((ext_vector_type(8))) short bf16x8;
typedef __attribute__((ext_vector_type(4))) float f32x4;

#define BDIM 4096
#define DDIM 1024
#define UDIM 1024
#define NE 8
#define NDIM 8192    // U*E
#define RL_CAP 4224  // per-expert rowlist capacity

__device__ __forceinline__ u16 f2bf(float f) {
    unsigned int u = __float_as_uint(f);
    u += 0x7fffu + ((u >> 16) & 1u);   // round-to-nearest-even
    return (u16)(u >> 16);
}

__device__ __forceinline__ void gload_lds16(const u16* g, u16* lds) {
    __builtin_amdgcn_global_load_lds(
        (const __attribute__((address_space(1))) void*)g,
        (__attribute__((address_space(3))) void*)lds, 16, 0, 0);
}

// ================= phase 1: mu->Wem transpose | gating+x->bf16 | se =================
// blocks [0,2048): transpose 64x64 tile of mu into expert-major bf16 Wem[e][u][d]
// blocks [2048,3072): gating for 4 rows each (+ xb bf16 write)
// blocks [3072,3104): se = softplus(rho)*eps
__global__ __launch_bounds__(256) void prep_kernel(
    const float* __restrict__ mu, const float* __restrict__ x,
    const float* __restrict__ gk, const float* __restrict__ gb,
    const float* __restrict__ rho, const float* __restrict__ eps,
    u16* __restrict__ Wem, u16* __restrict__ xb,
    float* __restrict__ gw, float* __restrict__ xsum,
    int4* __restrict__ pkb, float* __restrict__ se)
{
    __shared__ u16 tile[64 * 66];
    const int bx = blockIdx.x;
    const int tid = threadIdx.x;

    if (bx < 2048) {
        const int n0 = (bx & 127) << 6;
        const int d0 = (bx >> 7) << 6;
        const int nq = (tid & 15) << 2;
        const int dr = tid >> 4;             // 0..15
#pragma unroll
        for (int p = 0; p < 4; ++p) {
            int dl = p * 16 + dr;
            float4 v = *(const float4*)&mu[(size_t)(d0 + dl) * NDIM + n0 + nq];
            tile[dl * 66 + nq + 0] = f2bf(v.x);
            tile[dl * 66 + nq + 1] = f2bf(v.y);
            tile[dl * 66 + nq + 2] = f2bf(v.z);
            tile[dl * 66 + nq + 3] = f2bf(v.w);
        }
        __syncthreads();
#pragma unroll
        for (int issue = 0; issue < 2; ++issue) {
            int nloc = issue * 32 + (tid >> 3);
            int d8 = (tid & 7) * 8;
            uint4 o; u16* tp = (u16*)&o;
#pragma unroll
            for (int i = 0; i < 8; ++i) tp[i] = tile[(d8 + i) * 66 + nloc];
            int n = n0 + nloc;                       // original col = u*8+e
            int er = ((n & 7) << 10) | (n >> 3);     // expert-major row e*1024+u
            *(uint4*)&Wem[(size_t)er * DDIM + d0 + d8] = o;
        }
    } else if (bx < 3072) {
        const int b = (bx - 2048) * 4 + (tid >> 6);
        const int lane = tid & 63;
        float acc[8] = {0.f,0.f,0.f,0.f,0.f,0.f,0.f,0.f};
        float xs = 0.f;
        for (int d = lane; d < DDIM; d += 64) {
            float xv = x[(size_t)b * DDIM + d];
            xb[(size_t)b * DDIM + d] = f2bf(xv);
            xs += xv;
            const float4* g4 = (const float4*)&gk[d * NE];
            float4 g0 = g4[0], g1 = g4[1];
            acc[0] += xv * g0.x; acc[1] += xv * g0.y; acc[2] += xv * g0.z; acc[3] += xv * g0.w;
            acc[4] += xv * g1.x; acc[5] += xv * g1.y; acc[6] += xv * g1.z; acc[7] += xv * g1.w;
        }
#pragma unroll
        for (int off = 32; off >= 1; off >>= 1) {
            xs += __shfl_xor(xs, off);
#pragma unroll
            for (int e = 0; e < 8; ++e) acc[e] += __shfl_xor(acc[e], off);
        }
        if (lane == 0) {
            float lg[8];
#pragma unroll
            for (int e = 0; e < 8; ++e) lg[e] = acc[e] + gb[e];
            int i1 = 0;
#pragma unroll
            for (int e = 1; e < 8; ++e) if (lg[e] > lg[i1]) i1 = e;  // first-occurrence argmax
            int i2 = (i1 == 0) ? 1 : 0;
#pragma unroll
            for (int e = 0; e < 8; ++e) {
                if (e == i1 || e == i2) continue;
                if (lg[e] > lg[i2]) i2 = e;
            }
            float p1 = 1.f / (1.f + expf(lg[i2] - lg[i1]));  // renorm top-2 softmax
            float p2 = 1.f - p1;
            float out[8] = {0.f,0.f,0.f,0.f,0.f,0.f,0.f,0.f};
            out[i1] = p1; out[i2] = p2;
#pragma unroll
            for (int e = 0; e < 8; ++e) gw[b * NE + e] = out[e];
            xsum[b] = xs;
            pkb[b] = make_int4(i1, i2, __float_as_int(p1), __float_as_int(p2));
        }
    } else {
        int i = (bx - 3072) * 256 + tid;
        float r = rho[i];
        se[i] = log1pf(expf(r)) * eps[i];
    }
}

// ================= phase 2: rowlist build (blocks 0..7) | y init (blocks 8..) =================
__global__ __launch_bounds__(256) void mid_kernel(
    const int4* __restrict__ pkb, const float* __restrict__ xsum,
    const float* __restrict__ se, const float* __restrict__ biasv,
    int* __restrict__ cnt, u16* __restrict__ rowlist,
    float* __restrict__ y)
{
    const int bx = blockIdx.x;
    const int tid = threadIdx.x;
    if (bx < 8) {
        const int e = bx;
        const int wv = tid >> 6, lane = tid & 63;
        __shared__ int wsum[4];
        __shared__ int sbase;
        if (tid == 0) sbase = 0;
        __syncthreads();
        u16* rl = rowlist + e * RL_CAP;
        for (int chunk = 0; chunk < BDIM; chunk += 256) {
            int b = chunk + tid;
            int4 pk = pkb[b];
            bool f = (pk.x == e) || (pk.y == e);
            unsigned long long m = __ballot(f);
            int prefix = __popcll(m & ((1ULL << lane) - 1ULL));
            if (lane == 0) wsum[wv] = __popcll(m);
            __syncthreads();
            int wbase = sbase;
            for (int w = 0; w < wv; ++w) wbase += wsum[w];
            if (f) rl[wbase + prefix] = (u16)b;
            __syncthreads();
            if (tid == 0) sbase += wsum[0] + wsum[1] + wsum[2] + wsum[3];
            __syncthreads();
        }
        int c = sbase;
        int pc = (c + 127) & ~127;
        for (int i = c + tid; i < pc; i += 256) rl[i] = (u16)0xFFFF;
        if (tid == 0) cnt[e] = c;
    } else {
        int idx = (bx - 8) * 256 + tid;   // over B * U/4
        int b = idx >> 8;
        int u4 = (idx & 255) * 4;
        int4 pk = pkb[b];
        float w1 = __int_as_float(pk.z), w2 = __int_as_float(pk.w);
        float xs = xsum[b];
        float4 o;
#pragma unroll
        for (int t = 0; t < 4; ++t) {
            int u = u4 + t;
            int n1 = u * NE + pk.x, n2 = u * NE + pk.y;
            ((float*)&o)[t] = w1 * (xs * se[n1] + biasv[n1]) + w2 * (xs * se[n2] + biasv[n2]);
        }
        *(float4*)&y[(size_t)b * UDIM + u4] = o;
    }
}

// ================= grouped GEMM: 64x128 tile, BK=64, double-buffered 2-phase =================
// blockIdx.y: e = y>>6, m-slot = y&63 (64-row tiles); early-exit if m0 >= cnt[e].
// Wem is expert-major: row e*1024+u, so B-tile rows are contiguous.
__global__ __launch_bounds__(256, 3) void gemm_grouped_kernel(
    const u16* __restrict__ Xb,      // [4096][1024] bf16
    const u16* __restrict__ Wem,     // [8][1024][1024] bf16
    const float* __restrict__ gw,    // [4096][8]
    const int* __restrict__ cnt,     // [8]
    const u16* __restrict__ rowlist, // [8][RL_CAP]
    float* __restrict__ y)           // [4096][1024]
{
    const int e  = blockIdx.y >> 6;
    const int m0 = (blockIdx.y & 63) << 6;
    if (m0 >= cnt[e]) return;
    const int u0 = blockIdx.x << 7;

    __shared__ u16 As[2][64 * 64];
    __shared__ u16 Bs[2][128 * 64];

    const int tid  = threadIdx.x;
    const int lane = tid & 63;
    const int wid  = tid >> 6;
    const int wm = wid >> 1, wn = wid & 1;
    const int l15 = lane & 15;
    const int l4  = lane >> 4;

    const u16* __restrict__ rowl = rowlist + e * RL_CAP + m0;

    const int stg_r  = tid >> 3;        // 0..31
    const int stg_c8 = (tid & 7) * 8;   // 0..56

    const u16* aP[2];
    const u16* bP[4];
#pragma unroll
    for (int it = 0; it < 2; ++it) {
        int r = it * 32 + stg_r;
        int rid = rowl[r];
        if (rid == 0xFFFF) rid = 0;     // padded slot: any valid row
        aP[it] = Xb + (size_t)rid * DDIM + stg_c8;
    }
#pragma unroll
    for (int it = 0; it < 4; ++it) {
        int r = it * 32 + stg_r;
        bP[it] = Wem + ((size_t)((e << 10) + u0 + r)) * DDIM + stg_c8;
    }

#define STAGE(BUF, KK) do {                                                     \
        gload_lds16(aP[0] + (KK), &As[BUF][(stg_r) * 64 + stg_c8]);             \
        gload_lds16(aP[1] + (KK), &As[BUF][(32 + stg_r) * 64 + stg_c8]);        \
        gload_lds16(bP[0] + (KK), &Bs[BUF][(stg_r) * 64 + stg_c8]);             \
        gload_lds16(bP[1] + (KK), &Bs[BUF][(32 + stg_r) * 64 + stg_c8]);        \
        gload_lds16(bP[2] + (KK), &Bs[BUF][(64 + stg_r) * 64 + stg_c8]);        \
        gload_lds16(bP[3] + (KK), &Bs[BUF][(96 + stg_r) * 64 + stg_c8]);        \
    } while (0)

    f32x4 acc[2][4] = {};

    STAGE(0, 0);
    __syncthreads();
#pragma unroll
    for (int t = 0; t < 16; ++t) {
        const int cur = t & 1;
        if (t != 15) STAGE(cur ^ 1, (t + 1) * 64);
#pragma unroll
        for (int k2 = 0; k2 < 2; ++k2) {
            bf16x8 av[2], bv[4];
#pragma unroll
            for (int m = 0; m < 2; ++m)
                av[m] = *(const bf16x8*)&As[cur][(wm * 32 + m * 16 + l15) * 64 + k2 * 32 + l4 * 8];
#pragma unroll
            for (int n = 0; n < 4; ++n)
                bv[n] = *(const bf16x8*)&Bs[cur][(wn * 64 + n * 16 + l15) * 64 + k2 * 32 + l4 * 8];
#pragma unroll
            for (int m = 0; m < 2; ++m)
#pragma unroll
                for (int n = 0; n < 4; ++n)
                    acc[m][n] = __builtin_amdgcn_mfma_f32_16x16x32_bf16(av[m], bv[n], acc[m][n], 0, 0, 0);
        }
        __syncthreads();
    }
#undef STAGE

    // Epilogue: y[b,u] += gw[b,e] * dot  (C/D: col=lane&15, row=(lane>>4)*4+j)
#pragma unroll
    for (int m = 0; m < 2; ++m) {
#pragma unroll
        for (int jj = 0; jj < 4; ++jj) {
            int r_loc = wm * 32 + m * 16 + l4 * 4 + jj;
            u16 b16 = rowl[r_loc];
            if (b16 == (u16)0xFFFF) continue;
            float w = gw[(int)b16 * NE + e];
            float* yrow = &y[(size_t)b16 * UDIM];
#pragma unroll
            for (int n = 0; n < 4; ++n) {
                int u = u0 + wn * 64 + n * 16 + l15;
                atomicAdd(&yrow[u], w * acc[m][n][jj]);
            }
        }
    }
}

extern "C" void kernel_launch(void* const* d_in, const int* in_sizes, int n_in,
                              void* d_out, int out_size, void* d_ws, size_t ws_size,
                              hipStream_t stream) {
    const float* x    = (const float*)d_in[0];
    const float* mu   = (const float*)d_in[1];
    const float* rho  = (const float*)d_in[2];
    const float* bias = (const float*)d_in[3];
    const float* gk   = (const float*)d_in[4];
    const float* gb   = (const float*)d_in[5];
    const float* eps  = (const float*)d_in[6];
    float* y = (float*)d_out;

    char* ws = (char*)d_ws;
    u16*   Wem  = (u16*)ws;                       // 16,777,216
    u16*   xb   = (u16*)(ws + 16777216);          //  8,388,608 -> 25165824
    float* gwp  = (float*)(ws + 25165824);        //    131,072 -> 25296896
    float* xsp  = (float*)(ws + 25296896);        //     16,384 -> 25313280
    float* sep  = (float*)(ws + 25313280);        //     32,768 -> 25346048
    int*   cnt  = (int*)(ws + 25346048);          //         32 -> 25346080
    int4*  pkb  = (int4*)(ws + 25346560);         //     65,536 -> 25412096
    u16*   rowl = (u16*)(ws + 25412096);          //     67,584 -> 25479680
    if (ws_size < 25479680) return;

    prep_kernel<<<dim3(3104), dim3(256), 0, stream>>>(
        mu, x, gk, gb, rho, eps, Wem, xb, gwp, xsp, pkb, sep);
    mid_kernel<<<dim3(8 + BDIM * (UDIM / 4) / 256), dim3(256), 0, stream>>>(
        pkb, xsp, sep, bias, cnt, rowl, y);
    gemm_grouped_kernel<<<dim3(UDIM / 128, 512), dim3(256), 0, stream>>>(
        xb, Wem, gwp, cnt, rowl, y);
}